// Round 4
// baseline (293.378 us; speedup 1.0000x reference)
//
#include <hip/hip_runtime.h>
#include <hip/hip_bf16.h>

// B=4, S=2048, D=1024. q=relu(x Wq^T + bq) etc; out = softmax(q k^T) v.
// R8 = R7 resubmitted verbatim after a container-level infra failure (no
// counters returned; barrier/vmcnt/WAR/bounds re-audited — no hang path).
// R7: counted-vmcnt 256x256 pipelined GEMM core:
//   - BM=BN=256, BK=64, 8 waves (2Mx4N), per-wave 128x64, 32x32x16 MFMA
//   - 2 phases per K-tile, 16 MFMA each, split by M-quadrant; B-frags read
//     once at P0 and held in registers across the tile -> buffer lifetimes:
//     A-even rows {0-63,128-191} + all B free after P0; A-odd after P1
//   - stage rhythm: P0 stages Aodd(t+1) [2 gld], P1 stages Aeven+B(t+2)
//     [6 gld]; vmcnt(8) before every closing barrier (NEVER 0 in loop).
//     Outstanding-count invariant: 8 entering each P0; every load gets
//     >=2 phases (~850 cy) of cover. Prologue: tile0 full + tile1
//     {Aeven,B}, vmcnt(6). Tail clamps SOURCE k only (dest slot parity
//     preserved -> WAR-safe).
//   - R4/R6 evidence: LDS bank conflicts are global_load_lds WRITE-side
//     (8 cy/instr, fixed); ds_read pattern is conflict-free (8-lane group
//     covers all 8 chunks). XOR chunk swizzle cl = cp ^ (row&7) kept.
// Fused V-transpose epilogue + wave-softmax kept from R6. pv runs 128
// blocks (half-idle) this round — geometry specialization deferred.
//
// ws layout (128 MB):
//   [0,16)   q bf16           [16,32) k bf16
//   [48,64)  vt bf16 (written transposed by qkv z==2)
//   [64,128) logits fp32 (softmax overwrites rows in-place with bf16 probs)
//   xb bf16 aliases [64,80), Wb bf16 aliases [80,86) -- consumed by qkv
//   before qk writes logits (stream-ordered).

#define SEQ 2048
#define DIM 1024
#define NB 4
#define MTOT (NB * SEQ)   // 8192

typedef __attribute__((ext_vector_type(8))) short frag_ab;
typedef __attribute__((ext_vector_type(16))) float frag_c16;

__device__ __forceinline__ ushort f2bf(float f) {
    union { float f; unsigned u; } x; x.f = f;
    unsigned r = x.u + 0x7fffu + ((x.u >> 16) & 1u);  // RNE
    return (ushort)(r >> 16);
}

typedef __attribute__((address_space(1))) const unsigned int guint;
typedef __attribute__((address_space(3))) unsigned int luint;

__device__ __forceinline__ void gld_lds16(const void* g, void* l) {
    __builtin_amdgcn_global_load_lds((guint*)g, (luint*)l, 16, 0, 0);
}

__device__ __forceinline__ void bar() {
    asm volatile("" ::: "memory");
    __builtin_amdgcn_s_barrier();
    asm volatile("" ::: "memory");
}
#define VMCNT(n) asm volatile("s_waitcnt vmcnt(" #n ")" ::: "memory")

#define TS (256 * 64)   // one 256x64 bf16 tile slot = 32 KB

// Stage 64 rows x 64 k of a tile: one gld_lds16 per thread (512 thr x 16 B
// = 8 KB). Wave w covers rows row0+w*8..+7; lane chunk cp=lane&7; source
// pre-swizzled so logical chunk cl lands at physical chunk cl^(row&7)
// (LDS dest linear, as global_load_lds requires).
__device__ __forceinline__ void stage64(const ushort* __restrict__ P,
                                        size_t ld, int k0, ushort* dst,
                                        int row0, int wave, int lane)
{
    int row = row0 + wave * 8 + (lane >> 3);
    int cl  = (lane & 7) ^ (row & 7);
    gld_lds16(P + (size_t)row * ld + k0 + cl * 8, dst + (row0 + wave * 8) * 64);
}

// read 2 row-frags x 4 k-steps from a tile slot (swizzled chunks)
__device__ __forceinline__ void rdfrags(frag_ab (&f)[2][4], const ushort* S,
                                        int r0, int l32, int half)
{
    #pragma unroll
    for (int i = 0; i < 2; ++i) {
        int row = r0 + i * 32 + l32;
        int sw  = row & 7;
        #pragma unroll
        for (int ks = 0; ks < 4; ++ks)
            f[i][ks] = *(const frag_ab*)&S[row * 64 + ((ks * 2 + half) ^ sw) * 8];
    }
}

template<int MB>
__device__ __forceinline__ void mfma16(frag_c16 (&acc)[4][2],
                                       const frag_ab (&af)[2][4],
                                       const frag_ab (&bf)[2][4])
{
    __builtin_amdgcn_s_setprio(1);
    #pragma unroll
    for (int ks = 0; ks < 4; ++ks)
        #pragma unroll
        for (int mi = 0; mi < 2; ++mi)
            #pragma unroll
            for (int ni = 0; ni < 2; ++ni)
                acc[MB + mi][ni] = __builtin_amdgcn_mfma_f32_32x32x16_bf16(
                    af[mi][ks], bf[ni][ks], acc[MB + mi][ni], 0, 0, 0);
    __builtin_amdgcn_s_setprio(0);
}

// ---------------------------------------------------------------------------
// 256x256-tile counted-vmcnt mainloop. A,B pre-offset to tile row 0,
// K-contiguous (B^T convention), ld multiple of 8, K multiple of 128.
// Wave w: rows (w&1)*128, cols (w>>1)*64. Numerics: per-acc K-order is
// ks 0..3 per tile, tiles sequential == R6 exactly.
// ---------------------------------------------------------------------------
__device__ __forceinline__ void gemm256(
    const ushort* __restrict__ A, size_t lda,
    const ushort* __restrict__ B, size_t ldb, int K,
    ushort (&Ab)[2][TS], ushort (&Bb)[2][TS], frag_c16 (&acc)[4][2])
{
    const int tid  = threadIdx.x;
    const int wave = tid >> 6;
    const int lane = tid & 63;
    const int l32  = lane & 31;
    const int half = lane >> 5;
    const int wm   = (wave & 1) * 128;
    const int wn   = (wave >> 1) * 64;
    const int nkt  = K >> 6;

    // prologue: tile0 full (8 gld) + tile1 {Aeven,B} (6 gld) = 14 in flight
    stage64(A, lda, 0, Ab[0], 0,   wave, lane);
    stage64(A, lda, 0, Ab[0], 64,  wave, lane);
    stage64(A, lda, 0, Ab[0], 128, wave, lane);
    stage64(A, lda, 0, Ab[0], 192, wave, lane);
    stage64(B, ldb, 0, Bb[0], 0,   wave, lane);
    stage64(B, ldb, 0, Bb[0], 64,  wave, lane);
    stage64(B, ldb, 0, Bb[0], 128, wave, lane);
    stage64(B, ldb, 0, Bb[0], 192, wave, lane);
    stage64(A, lda, 64, Ab[1], 0,   wave, lane);
    stage64(A, lda, 64, Ab[1], 128, wave, lane);
    stage64(B, ldb, 64, Bb[1], 0,   wave, lane);
    stage64(B, ldb, 64, Bb[1], 64,  wave, lane);
    stage64(B, ldb, 64, Bb[1], 128, wave, lane);
    stage64(B, ldb, 64, Bb[1], 192, wave, lane);
    VMCNT(6);          // tile0's 8 loads landed
    bar();

    for (int t = 0; t < nkt; ++t) {
        const int p = t & 1;
        const ushort* Ap = Ab[p];
        const ushort* Bp = Bb[p];

        // ---- P0: M-quadrant lo (Aeven rows) + ALL B-frags (kept in regs)
        frag_ab af[2][4], bf[2][4];
        rdfrags(af, Ap, wm, l32, half);
        rdfrags(bf, Bp, wn, l32, half);
        {   // stage Aodd(t+1) -> other slot (its prior reads closed at
            // (t-1,P1).bar2); needed at (t+1,P1): 2 phases of cover
            int k1 = (t + 1 < nkt ? t + 1 : nkt - 1) * 64;
            stage64(A, lda, k1, Ab[p ^ 1], 64,  wave, lane);
            stage64(A, lda, k1, Ab[p ^ 1], 192, wave, lane);
        }
        bar();
        mfma16<0>(acc, af, bf);
        VMCNT(8);      // drains Aodd(t) (staged at (t-1).P0)
        bar();

        // ---- P1: M-quadrant hi (Aodd rows), B reused from registers
        frag_ab ag[2][4];
        rdfrags(ag, Ap, wm + 64, l32, half);
        {   // stage Aeven+B(t+2) -> THIS slot (Aeven/B(t) reads closed at
            // P0.bar2; disjoint from this phase's Aodd reads). Needed at
            // (t+2,P0): 2 phases of cover.
            int k2 = (t + 2 < nkt ? t + 2 : nkt - 1) * 64;
            stage64(A, lda, k2, Ab[p], 0,   wave, lane);
            stage64(A, lda, k2, Ab[p], 128, wave, lane);
            stage64(B, ldb, k2, Bb[p], 0,   wave, lane);
            stage64(B, ldb, k2, Bb[p], 64,  wave, lane);
            stage64(B, ldb, k2, Bb[p], 128, wave, lane);
            stage64(B, ldb, k2, Bb[p], 192, wave, lane);
        }
        bar();
        mfma16<2>(acc, ag, bf);
        VMCNT(8);      // drains the 6 Aeven+B(t+1) staged at (t-1).P1
        bar();
    }
    VMCNT(0);          // don't end waves with LDS writes in flight
}

// C/D layout (32x32): col = lane&31, row = (reg&3) + 8*(reg>>2) + 4*(lane>>5)

// ---------------------------------------------------------------------------
// fp32 -> bf16 converter, x + 3 weights in one launch (memory-bound)
// ---------------------------------------------------------------------------
#define NX4 (MTOT * DIM / 4)          // 2M float4 for x
#define NW4 (DIM * DIM / 4)           // 256K float4 per W
__global__ __launch_bounds__(256) void cvt_kernel(
    const float* __restrict__ x,
    const float* __restrict__ Wq, const float* __restrict__ Wk,
    const float* __restrict__ Wv,
    ushort* __restrict__ xb, ushort* __restrict__ Wb)
{
    size_t i = (size_t)blockIdx.x * 256 + threadIdx.x;
    const float* src; ushort* dst; size_t idx;
    if (i < NX4) { src = x; dst = xb; idx = i; }
    else {
        size_t j = i - NX4;
        int w = (int)(j >> 18);               // j / NW4
        idx = j & (NW4 - 1);
        src = w == 0 ? Wq : (w == 1 ? Wk : Wv);
        dst = Wb + (size_t)w * DIM * DIM;
    }
    float4 f = ((const float4*)src)[idx];
    ushort4 u; u.x = f2bf(f.x); u.y = f2bf(f.y); u.z = f2bf(f.z); u.w = f2bf(f.w);
    ((ushort4*)dst)[idx] = u;
}

// ---------------------------------------------------------------------------
// Kernel 1: q/k/v = relu(x W^T + b) -> bf16.  grid (32, 4, 3), block 512.
// z==0 -> q row-major, z==1 -> k row-major, z==2 -> V written TRANSPOSED
// into vt[bz][o][s] (r&3 packs 4 consecutive s -> ushort4 stores).
// ---------------------------------------------------------------------------
__global__ __launch_bounds__(512, 2) void qkv_kernel(
    const ushort* __restrict__ xb, const ushort* __restrict__ Wb,
    const float* __restrict__ bq, const float* __restrict__ bk,
    const float* __restrict__ bv,
    ushort* __restrict__ q, ushort* __restrict__ kk, ushort* __restrict__ vt)
{
    __shared__ ushort Ab[2][TS];
    __shared__ ushort Bb[2][TS];

    const float* bias;
    if (blockIdx.z == 0)      bias = bq;
    else if (blockIdx.z == 1) bias = bk;
    else                      bias = bv;
    const ushort* W = Wb + (size_t)blockIdx.z * DIM * DIM;

    const int m0 = blockIdx.x * 256;
    const int n0 = blockIdx.y * 256;

    frag_c16 acc[4][2] = {};
    gemm256(xb + (size_t)m0 * DIM, DIM, W + (size_t)n0 * DIM, DIM, DIM,
            Ab, Bb, acc);

    const int tid  = threadIdx.x;
    const int wave = tid >> 6;
    const int lane = tid & 63;
    const int l32  = lane & 31;
    const int half = lane >> 5;
    const int wm   = (wave & 1) * 128;
    const int wn   = (wave >> 1) * 64;

    if (blockIdx.z == 2) {
        // vt[bz][col][s]; tile rows never straddle a batch (256 | 2048)
        const int bz = m0 >> 11;
        const int sb = (m0 & (SEQ - 1)) + wm;
        #pragma unroll
        for (int ni = 0; ni < 2; ++ni) {
            int col = n0 + wn + ni * 32 + l32;
            float bb = bias[col];
            ushort* vrow = vt + ((size_t)(bz * DIM + col)) * SEQ;
            #pragma unroll
            for (int mi = 0; mi < 4; ++mi)
                #pragma unroll
                for (int g = 0; g < 4; ++g) {
                    int s0 = sb + mi * 32 + 8 * g + 4 * half;
                    ushort4 u;
                    #pragma unroll
                    for (int j = 0; j < 4; ++j) {
                        float val = acc[mi][ni][4 * g + j] + bb;
                        val = val > 0.0f ? val : 0.0f;
                        ((ushort*)&u)[j] = f2bf(val);
                    }
                    *(ushort4*)&vrow[s0] = u;
                }
        }
    } else {
        ushort* out = blockIdx.z == 0 ? q : kk;
        #pragma unroll
        for (int ni = 0; ni < 2; ++ni) {
            int col = n0 + wn + ni * 32 + l32;
            float bb = bias[col];
            #pragma unroll
            for (int mi = 0; mi < 4; ++mi)
                #pragma unroll
                for (int r = 0; r < 16; ++r) {
                    int row = m0 + wm + mi * 32 + (r & 3) + 8 * (r >> 2) + 4 * half;
                    float val = acc[mi][ni][r] + bb;
                    val = val > 0.0f ? val : 0.0f;
                    out[(size_t)row * DIM + col] = f2bf(val);
                }
        }
    }
}

// ---------------------------------------------------------------------------
// Kernel 3: logits = q k^T (fp32).  grid (8,8,4), block 512
// ---------------------------------------------------------------------------
__global__ __launch_bounds__(512, 2) void qk_kernel(
    const ushort* __restrict__ q, const ushort* __restrict__ kk,
    float* __restrict__ logits)
{
    __shared__ ushort Ab[2][TS];
    __shared__ ushort Bb[2][TS];

    const int bz = blockIdx.z;
    const int m0 = blockIdx.x * 256;
    const int n0 = blockIdx.y * 256;
    const size_t base = (size_t)bz * SEQ;

    frag_c16 acc[4][2] = {};
    gemm256(q + (base + m0) * DIM, DIM, kk + (base + n0) * DIM, DIM, DIM,
            Ab, Bb, acc);

    const int tid  = threadIdx.x;
    const int wave = tid >> 6;
    const int lane = tid & 63;
    const int l32  = lane & 31;
    const int half = lane >> 5;
    const int wm   = (wave & 1) * 128;
    const int wn   = (wave >> 1) * 64;

    #pragma unroll
    for (int mi = 0; mi < 4; ++mi)
        #pragma unroll
        for (int r = 0; r < 16; ++r) {
            int row = m0 + wm + mi * 32 + (r & 3) + 8 * (r >> 2) + 4 * half;
            #pragma unroll
            for (int ni = 0; ni < 2; ++ni) {
                int col = n0 + wn + ni * 32 + l32;
                logits[(base + row) * SEQ + col] = acc[mi][ni][r];
            }
        }
}

// ---------------------------------------------------------------------------
// Kernel 4: row softmax over 2048 fp32, write bf16 probs in-place.
// 1 wave per row, 4 rows per block, no LDS / no barriers.
// ---------------------------------------------------------------------------
__global__ __launch_bounds__(256) void softmax_kernel(float* __restrict__ logits)
{
    const int row  = blockIdx.x * 4 + (threadIdx.x >> 6);
    const int lane = threadIdx.x & 63;
    float* p = logits + (size_t)row * SEQ;

    float4 x[8];
    #pragma unroll
    for (int i = 0; i < 8; ++i) x[i] = ((const float4*)p)[lane + 64 * i];

    float m = -3.4e38f;
    #pragma unroll
    for (int i = 0; i < 8; ++i)
        m = fmaxf(m, fmaxf(fmaxf(x[i].x, x[i].y), fmaxf(x[i].z, x[i].w)));
    #pragma unroll
    for (int off = 32; off; off >>= 1) m = fmaxf(m, __shfl_xor(m, off, 64));

    float s = 0.0f;
    #pragma unroll
    for (int i = 0; i < 8; ++i) {
        x[i].x = __expf(x[i].x - m); x[i].y = __expf(x[i].y - m);
        x[i].z = __expf(x[i].z - m); x[i].w = __expf(x[i].w - m);
        s += (x[i].x + x[i].y) + (x[i].z + x[i].w);
    }
    #pragma unroll
    for (int off = 32; off; off >>= 1) s += __shfl_xor(s, off, 64);
    float inv = 1.0f / s;

    ushort* o = (ushort*)p;
    #pragma unroll
    for (int i = 0; i < 8; ++i) {
        ushort4 u;
        u.x = f2bf(x[i].x * inv); u.y = f2bf(x[i].y * inv);
        u.z = f2bf(x[i].z * inv); u.w = f2bf(x[i].w * inv);
        ((ushort4*)o)[lane + 64 * i] = u;
    }
}

// ---------------------------------------------------------------------------
// Kernel 5: out = P vt^T (fp32). P rows stride 4096 ushorts. grid (8,4,4).
// 128 blocks = half the CUs idle this round (geometry specialization TBD).
// ---------------------------------------------------------------------------
__global__ __launch_bounds__(512, 2) void pv_kernel(
    const ushort* __restrict__ probs, const ushort* __restrict__ vt,
    float* __restrict__ out)
{
    __shared__ ushort Ab[2][TS];
    __shared__ ushort Bb[2][TS];

    const int bz = blockIdx.z;
    const int m0 = blockIdx.x * 256;
    const int n0 = blockIdx.y * 256;

    frag_c16 acc[4][2] = {};
    gemm256(probs + ((size_t)(bz * SEQ + m0)) * 4096, 4096,
            vt + ((size_t)(bz * DIM + n0)) * SEQ, SEQ, SEQ,
            Ab, Bb, acc);

    const int tid  = threadIdx.x;
    const int wave = tid >> 6;
    const int lane = tid & 63;
    const int l32  = lane & 31;
    const int half = lane >> 5;
    const int wm   = (wave & 1) * 128;
    const int wn   = (wave >> 1) * 64;

    #pragma unroll
    for (int mi = 0; mi < 4; ++mi)
        #pragma unroll
        for (int r = 0; r < 16; ++r) {
            int row = m0 + wm + mi * 32 + (r & 3) + 8 * (r >> 2) + 4 * half;
            #pragma unroll
            for (int ni = 0; ni < 2; ++ni) {
                int col = n0 + wn + ni * 32 + l32;
                out[((size_t)(bz * SEQ + row)) * DIM + col] = acc[mi][ni][r];
            }
        }
}

// ---------------------------------------------------------------------------
extern "C" void kernel_launch(void* const* d_in, const int* in_sizes, int n_in,
                              void* d_out, int out_size, void* d_ws, size_t ws_size,
                              hipStream_t stream)
{
    const float* x  = (const float*)d_in[0];
    const float* Wq = (const float*)d_in[1];
    const float* bq = (const float*)d_in[2];
    const float* Wk = (const float*)d_in[3];
    const float* bk = (const float*)d_in[4];
    const float* Wv = (const float*)d_in[5];
    const float* bv = (const float*)d_in[6];
    float* out = (float*)d_out;

    char* ws = (char*)d_ws;
    ushort* q      = (ushort*)(ws);                           // 16 MB
    ushort* kk     = (ushort*)(ws + ((size_t)16 << 20));      // 16 MB
    ushort* vt     = (ushort*)(ws + ((size_t)48 << 20));      // 16 MB
    float*  logits = (float*) (ws + ((size_t)64 << 20));      // 64 MB
    ushort* xb     = (ushort*)(ws + ((size_t)64 << 20));      // aliases logits
    ushort* Wb     = (ushort*)(ws + ((size_t)80 << 20));      // aliases logits

    cvt_kernel<<<dim3((NX4 + 3 * NW4) / 256), 256, 0, stream>>>(
        x, Wq, Wk, Wv, xb, Wb);

    qkv_kernel<<<dim3(MTOT / 256, DIM / 256, 3), 512, 0, stream>>>(
        xb, Wb, bq, bk, bv, q, kk, vt);
    qk_kernel<<<dim3(SEQ / 256, SEQ / 256, NB), 512, 0, stream>>>(q, kk, logits);
    softmax_kernel<<<NB * SEQ / 4, 256, 0, stream>>>(logits);
    pv_kernel<<<dim3(SEQ / 256, DIM / 256, NB), 512, 0, stream>>>(
        (const ushort*)logits, vt, out);
}

// Round 5
// 280.366 us; speedup vs baseline: 1.0464x; 1.0464x over previous
//
#include <hip/hip_runtime.h>
#include <hip/hip_bf16.h>

// B=4, S=2048, D=1024. q=relu(x Wq^T + bq) etc; out = softmax(q k^T) v.
// R9: consolidation of measured-best pieces after two failed 256x256
// schedule ports (R5: -28us, R7: -57us vs R6; both post-mortemed — core
// +15% at best, killed by grid tails and coarse phase structure):
//   - GEMM core: R4's 128x128 BK=32 single-buffered loop VERBATIM
//     (measured 69.2us / 746 TF on qkv, best of session; multi-block/CU
//     gives implicit cross-block overlap of the barrier drain)
//   - qkv: R6's fused V-transpose epilogue (z==2 writes vt directly;
//     kills the transpose kernel + 32 MB traffic) — validated in R6
//   - softmax: R6's 1-wave-per-row barrier-free version — validated
//   - all grids exact multiples of 256 CUs (6.0 / 4.0 / 2.0 rounds)
// Known-invariant: SQ_LDS_BANK_CONFLICT ~6.29M regardless of swizzle/BK
// (global_load_lds write-side, small fixed cost — not a lever).
//
// ws layout (128 MB):
//   [0,16)   q bf16           [16,32) k bf16
//   [48,64)  vt bf16 (written transposed by qkv z==2)
//   [64,128) logits fp32 (softmax overwrites rows in-place with bf16 probs)
//   xb bf16 aliases [64,80), Wb bf16 aliases [80,86) -- consumed by qkv
//   before qk writes logits (stream-ordered).

#define SEQ 2048
#define DIM 1024
#define NB 4
#define MTOT (NB * SEQ)   // 8192

typedef __attribute__((ext_vector_type(8))) short frag_ab;
typedef __attribute__((ext_vector_type(16))) float frag_c16;

__device__ __forceinline__ ushort f2bf(float f) {
    union { float f; unsigned u; } x; x.f = f;
    unsigned r = x.u + 0x7fffu + ((x.u >> 16) & 1u);  // RNE
    return (ushort)(r >> 16);
}

typedef __attribute__((address_space(1))) const unsigned int guint;
typedef __attribute__((address_space(3))) unsigned int luint;

__device__ __forceinline__ void gld_lds16(const void* g, void* l) {
    __builtin_amdgcn_global_load_lds((guint*)g, (luint*)l, 16, 0, 0);
}

// ---------------------------------------------------------------------------
// 128x128-tile bf16 MFMA mainloop, 32x32x16 shape, BK=32, single-buffered.
// (R4 core, measured 746 TF in-situ.) A,B pre-offset to tile row 0,
// K-contiguous (B^T convention), lda/ldb multiples of 8.
// LDS tiles 128x32 unpadded; global 16B-chunk cg of row r stored at physical
// chunk cg ^ ((r>>1)&3). Wave w owns the 64x64 subtile (wm,wn), split 2x2
// into 32x32 MFMA tiles.
// ---------------------------------------------------------------------------
__device__ __forceinline__ void gemm_tiles(
    const ushort* __restrict__ A, size_t lda,
    const ushort* __restrict__ B, size_t ldb, int K,
    ushort* As, ushort* Bs, frag_c16 (&acc)[2][2])
{
    const int tid  = threadIdx.x;
    const int wave = tid >> 6;
    const int lane = tid & 63;
    const int l32  = lane & 31;
    const int half = lane >> 5;
    const int sr = wave * 16 + (lane >> 2);   // staging row (within 64-row half)
    const int sc = lane & 3;                  // staging physical chunk slot
    const int wm = (wave & 1) * 64;
    const int wn = (wave >> 1) * 64;

    for (int k0 = 0; k0 < K; k0 += 32) {
        #pragma unroll
        for (int j = 0; j < 2; ++j) {
            int row = j * 64 + sr;
            int cg  = sc ^ ((row >> 1) & 3);          // swizzled source chunk
            ushort* la = As + (j * 64 + wave * 16) * 32;  // wave-uniform base
            ushort* lb = Bs + (j * 64 + wave * 16) * 32;
            gld_lds16(A + (size_t)row * lda + k0 + cg * 8, la);
            gld_lds16(B + (size_t)row * ldb + k0 + cg * 8, lb);
        }
        __syncthreads();
        frag_ab af[2][2], bfr[2][2];
        #pragma unroll
        for (int mi = 0; mi < 2; ++mi) {
            int row = wm + mi * 32 + l32;
            int sw = (row >> 1) & 3;
            #pragma unroll
            for (int h = 0; h < 2; ++h) {
                int c = (h * 2 + half) ^ sw;
                af[mi][h] = *(const frag_ab*)&As[row * 32 + c * 8];
            }
        }
        #pragma unroll
        for (int ni = 0; ni < 2; ++ni) {
            int row = wn + ni * 32 + l32;
            int sw = (row >> 1) & 3;
            #pragma unroll
            for (int h = 0; h < 2; ++h) {
                int c = (h * 2 + half) ^ sw;
                bfr[ni][h] = *(const frag_ab*)&Bs[row * 32 + c * 8];
            }
        }
        #pragma unroll
        for (int h = 0; h < 2; ++h)
            #pragma unroll
            for (int mi = 0; mi < 2; ++mi)
                #pragma unroll
                for (int ni = 0; ni < 2; ++ni)
                    acc[mi][ni] = __builtin_amdgcn_mfma_f32_32x32x16_bf16(
                        af[mi][h], bfr[ni][h], acc[mi][ni], 0, 0, 0);
        __syncthreads();
    }
}

// C/D layout (32x32): col = lane&31, row = (reg&3) + 8*(reg>>2) + 4*(lane>>5)

// ---------------------------------------------------------------------------
// fp32 -> bf16 converter, x + 3 weights in one launch (memory-bound)
// ---------------------------------------------------------------------------
#define NX4 (MTOT * DIM / 4)          // 2M float4 for x
#define NW4 (DIM * DIM / 4)           // 256K float4 per W
__global__ __launch_bounds__(256) void cvt_kernel(
    const float* __restrict__ x,
    const float* __restrict__ Wq, const float* __restrict__ Wk,
    const float* __restrict__ Wv,
    ushort* __restrict__ xb, ushort* __restrict__ Wb)
{
    size_t i = (size_t)blockIdx.x * 256 + threadIdx.x;
    const float* src; ushort* dst; size_t idx;
    if (i < NX4) { src = x; dst = xb; idx = i; }
    else {
        size_t j = i - NX4;
        int w = (int)(j >> 18);               // j / NW4
        idx = j & (NW4 - 1);
        src = w == 0 ? Wq : (w == 1 ? Wk : Wv);
        dst = Wb + (size_t)w * DIM * DIM;
    }
    float4 f = ((const float4*)src)[idx];
    ushort4 u; u.x = f2bf(f.x); u.y = f2bf(f.y); u.z = f2bf(f.z); u.w = f2bf(f.w);
    ((ushort4*)dst)[idx] = u;
}

// ---------------------------------------------------------------------------
// Kernel 1: q/k/v = relu(x W^T + b) -> bf16.  grid (64, 8, 3), block 256.
// z==0 -> q row-major, z==1 -> k row-major, z==2 -> V written TRANSPOSED
// into vt[bz][o][s] (r&3 packs 4 consecutive s -> ushort4 stores).
// ---------------------------------------------------------------------------
__global__ __launch_bounds__(256) void qkv_kernel(
    const ushort* __restrict__ xb, const ushort* __restrict__ Wb,
    const float* __restrict__ bq, const float* __restrict__ bk,
    const float* __restrict__ bv,
    ushort* __restrict__ q, ushort* __restrict__ kk, ushort* __restrict__ vt)
{
    const float* bias;
    if (blockIdx.z == 0)      bias = bq;
    else if (blockIdx.z == 1) bias = bk;
    else                      bias = bv;
    const ushort* W = Wb + (size_t)blockIdx.z * DIM * DIM;

    __shared__ ushort As[128 * 32];
    __shared__ ushort Bs[128 * 32];

    const int tid  = threadIdx.x;
    const int wave = tid >> 6;
    const int lane = tid & 63;
    const int l32  = lane & 31;
    const int half = lane >> 5;
    const int m0 = blockIdx.x * 128;
    const int n0 = blockIdx.y * 128;
    const int wm = (wave & 1) * 64;
    const int wn = (wave >> 1) * 64;

    frag_c16 acc[2][2] = {};
    gemm_tiles(xb + (size_t)m0 * DIM, DIM, W + (size_t)n0 * DIM, DIM, DIM,
               As, Bs, acc);

    if (blockIdx.z == 2) {
        // vt[bz][col][s]; tile rows never straddle a batch (128 | 2048)
        const int bz = m0 >> 11;
        const int sb = (m0 & (SEQ - 1)) + wm;
        #pragma unroll
        for (int ni = 0; ni < 2; ++ni) {
            int col = n0 + wn + ni * 32 + l32;
            float bb = bias[col];
            ushort* vrow = vt + ((size_t)(bz * DIM + col)) * SEQ;
            #pragma unroll
            for (int mi = 0; mi < 2; ++mi)
                #pragma unroll
                for (int g = 0; g < 4; ++g) {
                    int s0 = sb + mi * 32 + 8 * g + 4 * half;
                    ushort4 u;
                    #pragma unroll
                    for (int j = 0; j < 4; ++j) {
                        float val = acc[mi][ni][4 * g + j] + bb;
                        val = val > 0.0f ? val : 0.0f;
                        ((ushort*)&u)[j] = f2bf(val);
                    }
                    *(ushort4*)&vrow[s0] = u;
                }
        }
    } else {
        ushort* out = blockIdx.z == 0 ? q : kk;
        #pragma unroll
        for (int ni = 0; ni < 2; ++ni) {
            int col = n0 + wn + ni * 32 + l32;
            float bb = bias[col];
            #pragma unroll
            for (int mi = 0; mi < 2; ++mi)
                #pragma unroll
                for (int r = 0; r < 16; ++r) {
                    int row = m0 + wm + mi * 32 + (r & 3) + 8 * (r >> 2) + 4 * half;
                    float val = acc[mi][ni][r] + bb;
                    val = val > 0.0f ? val : 0.0f;
                    out[(size_t)row * DIM + col] = f2bf(val);
                }
        }
    }
}

// ---------------------------------------------------------------------------
// Kernel 3: logits = q k^T (fp32).  grid (16,16,4)
// ---------------------------------------------------------------------------
__global__ __launch_bounds__(256) void qk_kernel(
    const ushort* __restrict__ q, const ushort* __restrict__ kk,
    float* __restrict__ logits)
{
    __shared__ ushort As[128 * 32];
    __shared__ ushort Bs[128 * 32];

    const int tid  = threadIdx.x;
    const int wave = tid >> 6;
    const int lane = tid & 63;
    const int l32  = lane & 31;
    const int half = lane >> 5;
    const int bz = blockIdx.z;
    const int m0 = blockIdx.x * 128;
    const int n0 = blockIdx.y * 128;
    const int wm = (wave & 1) * 64;
    const int wn = (wave >> 1) * 64;
    const size_t base = (size_t)bz * SEQ;

    frag_c16 acc[2][2] = {};
    gemm_tiles(q + (base + m0) * DIM, DIM, kk + (base + n0) * DIM, DIM, DIM,
               As, Bs, acc);

    #pragma unroll
    for (int mi = 0; mi < 2; ++mi)
        #pragma unroll
        for (int r = 0; r < 16; ++r) {
            int row = m0 + wm + mi * 32 + (r & 3) + 8 * (r >> 2) + 4 * half;
            #pragma unroll
            for (int ni = 0; ni < 2; ++ni) {
                int col = n0 + wn + ni * 32 + l32;
                logits[(base + row) * SEQ + col] = acc[mi][ni][r];
            }
        }
}

// ---------------------------------------------------------------------------
// Kernel 4: row softmax over 2048 fp32, write bf16 probs in-place.
// 1 wave per row, 4 rows per block, no LDS / no barriers.
// ---------------------------------------------------------------------------
__global__ __launch_bounds__(256) void softmax_kernel(float* __restrict__ logits)
{
    const int row  = blockIdx.x * 4 + (threadIdx.x >> 6);
    const int lane = threadIdx.x & 63;
    float* p = logits + (size_t)row * SEQ;

    float4 x[8];
    #pragma unroll
    for (int i = 0; i < 8; ++i) x[i] = ((const float4*)p)[lane + 64 * i];

    float m = -3.4e38f;
    #pragma unroll
    for (int i = 0; i < 8; ++i)
        m = fmaxf(m, fmaxf(fmaxf(x[i].x, x[i].y), fmaxf(x[i].z, x[i].w)));
    #pragma unroll
    for (int off = 32; off; off >>= 1) m = fmaxf(m, __shfl_xor(m, off, 64));

    float s = 0.0f;
    #pragma unroll
    for (int i = 0; i < 8; ++i) {
        x[i].x = __expf(x[i].x - m); x[i].y = __expf(x[i].y - m);
        x[i].z = __expf(x[i].z - m); x[i].w = __expf(x[i].w - m);
        s += (x[i].x + x[i].y) + (x[i].z + x[i].w);
    }
    #pragma unroll
    for (int off = 32; off; off >>= 1) s += __shfl_xor(s, off, 64);
    float inv = 1.0f / s;

    ushort* o = (ushort*)p;
    #pragma unroll
    for (int i = 0; i < 8; ++i) {
        ushort4 u;
        u.x = f2bf(x[i].x * inv); u.y = f2bf(x[i].y * inv);
        u.z = f2bf(x[i].z * inv); u.w = f2bf(x[i].w * inv);
        ((ushort4*)o)[lane + 64 * i] = u;
    }
}

// ---------------------------------------------------------------------------
// Kernel 5: out = P vt^T (fp32). P rows stride 4096 ushorts. grid (16,8,4)
// ---------------------------------------------------------------------------
__global__ __launch_bounds__(256) void pv_kernel(
    const ushort* __restrict__ probs, const ushort* __restrict__ vt,
    float* __restrict__ out)
{
    __shared__ ushort As[128 * 32];
    __shared__ ushort Bs[128 * 32];

    const int tid  = threadIdx.x;
    const int wave = tid >> 6;
    const int lane = tid & 63;
    const int l32  = lane & 31;
    const int half = lane >> 5;
    const int bz = blockIdx.z;
    const int m0 = blockIdx.x * 128;
    const int n0 = blockIdx.y * 128;
    const int wm = (wave & 1) * 64;
    const int wn = (wave >> 1) * 64;

    frag_c16 acc[2][2] = {};
    gemm_tiles(probs + ((size_t)(bz * SEQ + m0)) * 4096, 4096,
               vt + ((size_t)(bz * DIM + n0)) * SEQ, SEQ, SEQ,
               As, Bs, acc);

    #pragma unroll
    for (int mi = 0; mi < 2; ++mi)
        #pragma unroll
        for (int r = 0; r < 16; ++r) {
            int row = m0 + wm + mi * 32 + (r & 3) + 8 * (r >> 2) + 4 * half;
            #pragma unroll
            for (int ni = 0; ni < 2; ++ni) {
                int col = n0 + wn + ni * 32 + l32;
                out[((size_t)(bz * SEQ + row)) * DIM + col] = acc[mi][ni][r];
            }
        }
}

// ---------------------------------------------------------------------------
extern "C" void kernel_launch(void* const* d_in, const int* in_sizes, int n_in,
                              void* d_out, int out_size, void* d_ws, size_t ws_size,
                              hipStream_t stream)
{
    const float* x  = (const float*)d_in[0];
    const float* Wq = (const float*)d_in[1];
    const float* bq = (const float*)d_in[2];
    const float* Wk = (const float*)d_in[3];
    const float* bk = (const float*)d_in[4];
    const float* Wv = (const float*)d_in[5];
    const float* bv = (const float*)d_in[6];
    float* out = (float*)d_out;

    char* ws = (char*)d_ws;
    ushort* q      = (ushort*)(ws);                           // 16 MB
    ushort* kk     = (ushort*)(ws + ((size_t)16 << 20));      // 16 MB
    ushort* vt     = (ushort*)(ws + ((size_t)48 << 20));      // 16 MB
    float*  logits = (float*) (ws + ((size_t)64 << 20));      // 64 MB
    ushort* xb     = (ushort*)(ws + ((size_t)64 << 20));      // aliases logits
    ushort* Wb     = (ushort*)(ws + ((size_t)80 << 20));      // aliases logits

    cvt_kernel<<<dim3((NX4 + 3 * NW4) / 256), 256, 0, stream>>>(
        x, Wq, Wk, Wv, xb, Wb);

    qkv_kernel<<<dim3(MTOT / 128, DIM / 128, 3), 256, 0, stream>>>(
        xb, Wb, bq, bk, bv, q, kk, vt);
    qk_kernel<<<dim3(SEQ / 128, SEQ / 128, NB), 256, 0, stream>>>(q, kk, logits);
    softmax_kernel<<<NB * SEQ / 4, 256, 0, stream>>>(logits);
    pv_kernel<<<dim3(SEQ / 128, DIM / 128, NB), 256, 0, stream>>>(
        (const ushort*)logits, vt, out);
}